// Round 12
// baseline (405.994 us; speedup 1.0000x reference)
//
#include <hip/hip_runtime.h>
#include <stdint.h>

#define T_LEN 512
#define NTOK  1536   // (1+NGRAM)*T
#define EMB   1024
#define BS    4

typedef __bf16 bf16x8 __attribute__((ext_vector_type(8)));
typedef float  f32x4  __attribute__((ext_vector_type(4)));

__device__ __forceinline__ float bflo(unsigned short u){
  union { unsigned int i; float f; } a; a.i = ((unsigned int)u) << 16; return a.f;
}
__device__ __forceinline__ unsigned short f2bf(float f){
  union { float f; unsigned int i; } v; v.f = f;
  unsigned int x = v.i;
  return (unsigned short)((x + 0x7fffu + ((x >> 16) & 1u)) >> 16); // RNE
}

// ---------------------------------------------------------------------------
// fp32 -> bf16 cast pre-pass (hidden, wqkv++relw, outw). 8 elems/thread.
// ---------------------------------------------------------------------------
__global__ __launch_bounds__(256)
void cast_k(const float* __restrict__ h, const float* __restrict__ wq,
            const float* __restrict__ rw, const float* __restrict__ ow,
            unsigned short* __restrict__ Hb, unsigned short* __restrict__ Wc,
            unsigned short* __restrict__ Ob)
{
  const size_t e = ((size_t)blockIdx.x * 256 + threadIdx.x) * 8;
  const float* src; unsigned short* dst;
  if (e < 6291456)            { src = h  + e;                 dst = Hb + e; }
  else if (e < 9437184)       { size_t o = e - 6291456;       src = wq + o; dst = Wc + o; }
  else if (e < 9961472)       { size_t o = e - 9437184;       src = rw + o; dst = Wc + 3145728 + o; }
  else                        { size_t o = e - 9961472;       src = ow + o; dst = Ob + o; }
  float4 f0 = *(const float4*)src, f1 = *(const float4*)(src + 4);
  unsigned short r[8];
  r[0]=f2bf(f0.x); r[1]=f2bf(f0.y); r[2]=f2bf(f0.z); r[3]=f2bf(f0.w);
  r[4]=f2bf(f1.x); r[5]=f2bf(f1.y); r[6]=f2bf(f1.z); r[7]=f2bf(f1.w);
  *(uint4*)dst = *(const uint4*)r;
}

// ---------------------------------------------------------------------------
// bf16 MFMA GEMM, C^T orientation, LDS-FREE K-loop: each wave loads its own
// W/A fragments directly global->register (16B/lane contiguous, full 64B
// lines) and issues 16 MFMA per BK=32. NO __syncthreads in the loop — waves
// fully decoupled, latency hidden by multi-wave occupancy + compiler vmcnt
// pipelining (the m97 2-barrier structure's vmcnt(0) drain is gone; R10/R11
// showed it capped MfmaUtil at ~18% for K=1024). Cross-wave reuse via L1/L2
// (W 7.3MB, A 12.6MB — L2-resident).
// Block = 128 cols x 128 tokens, 2x2 waves, wave = 64x64 via 4x4 frags.
// MODE 0: W=Wc(3584 rows: 3072 qkv + 512 rel), A=Hb. Epilogue: Q(x0.125)/K
//   direct 32B-sector uint2 -> [bh][tok][64]; V via 10KB LDS transpose ->
//   VT[bh][d][tok]; rel via fp32 LDS transpose -> VALS-T [bb][nb][h][tok].
// MODE 1: W=Ob(outw), A=ATTb, +outb -> fp32 d_out via float4.
// ---------------------------------------------------------------------------
template<int MODE>
__global__ __launch_bounds__(256, 2)
void mgemm(const unsigned short* __restrict__ A,
           const unsigned short* __restrict__ W,
           const float* __restrict__ B0,
           const float* __restrict__ B1,
           unsigned short* __restrict__ Qo, unsigned short* __restrict__ Ko,
           unsigned short* __restrict__ Vo, float* __restrict__ VALS,
           float* __restrict__ OUT)
{
  __shared__ __align__(16) unsigned short Ts[5120];  // epilogue transpose only
  const int K = 1024;
  const int m0 = blockIdx.y * 128, n0 = blockIdx.x * 128;
  const int tid = threadIdx.x;
  const int wid = tid >> 6, lane = tid & 63;
  const int l15 = lane & 15, q8 = (lane >> 4) * 8;
  const int wcol = (wid >> 1) * 64;
  const int wtok = (wid & 1) * 64;

  const unsigned short* wp[4];
  const unsigned short* ap[4];
  #pragma unroll
  for (int i=0;i<4;i++) wp[i] = W + (size_t)(n0 + wcol + i*16 + l15)*K + q8;
  #pragma unroll
  for (int j=0;j<4;j++) ap[j] = A + (size_t)(m0 + wtok + j*16 + l15)*K + q8;

  f32x4 acc[4][4];
  #pragma unroll
  for (int i=0;i<4;i++)
    #pragma unroll
    for (int j=0;j<4;j++)
      #pragma unroll
      for (int r=0;r<4;r++) acc[i][j][r] = 0.f;

  #pragma unroll 2
  for (int k0 = 0; k0 < K; k0 += 32) {
    bf16x8 wf[4], hf[4];
    #pragma unroll
    for (int i=0;i<4;i++) wf[i] = *(const bf16x8*)(wp[i] + k0);
    #pragma unroll
    for (int j=0;j<4;j++) hf[j] = *(const bf16x8*)(ap[j] + k0);
    #pragma unroll
    for (int i=0;i<4;i++)
      #pragma unroll
      for (int j=0;j<4;j++)
        acc[i][j] = __builtin_amdgcn_mfma_f32_16x16x32_bf16(wf[i], hf[j], acc[i][j], 0, 0, 0);
  }
  // D layout per lane: n(token-local)=l15(+16j+wtok), m(out-col)=rbase+r(+16i+wcol)
  const int rbase = (lane >> 4) * 4;

  if (MODE == 1) {
    #pragma unroll
    for (int i=0;i<4;i++){
      const int c0l = wcol + i*16 + rbase;
      float4 b4 = *(const float4*)&B0[n0 + c0l];
      #pragma unroll
      for (int j=0;j<4;j++){
        const int tokrow = m0 + wtok + j*16 + l15;
        float4 st; st.x=acc[i][j][0]+b4.x; st.y=acc[i][j][1]+b4.y;
        st.z=acc[i][j][2]+b4.z; st.w=acc[i][j][3]+b4.w;
        *(float4*)&OUT[(size_t)tokrow*EMB + n0 + c0l] = st;
      }
    }
    return;
  }

  // ---------------- MODE 0 epilogue (R9-verbatim paths) ----------------
  if (n0 < 2048) {
    // Q or K: direct uint2 (32B-sector-aligned across q4 lanes)
    const float sc = (n0 < 1024) ? 0.125f : 1.0f;
    unsigned short* base = (n0 < 1024) ? Qo : Ko;
    #pragma unroll
    for (int i=0;i<4;i++){
      const int cg = n0 + wcol + i*16 + rbase;
      const int hh = (cg & 1023) >> 6;
      const int d0 = cg & 63;
      float4 b4 = *(const float4*)&B0[cg];
      #pragma unroll
      for (int j=0;j<4;j++){
        const int tokrow = m0 + wtok + j*16 + l15;
        const int tok = tokrow >> 2, bb2 = tokrow & 3;
        unsigned short pk[4];
        pk[0]=f2bf((acc[i][j][0]+b4.x)*sc); pk[1]=f2bf((acc[i][j][1]+b4.y)*sc);
        pk[2]=f2bf((acc[i][j][2]+b4.z)*sc); pk[3]=f2bf((acc[i][j][3]+b4.w)*sc);
        *(uint2*)&base[((size_t)(bb2*16+hh)*NTOK + tok)*64 + d0] = *(const uint2*)pk;
      }
    }
  } else if (n0 < 3072) {
    // V: transpose via LDS (Ts[32 d][4 bb][40 tok-pad] shorts = 10.2 KB)
    const int tok0 = m0 >> 2;
    #pragma unroll
    for (int ch=0; ch<2; ++ch){
      const int hh = ((n0 + ch*64) & 1023) >> 6;
      #pragma unroll
      for (int dh=0; dh<2; ++dh){
        if ((wid >> 1) == ch){
          #pragma unroll
          for (int ii=0; ii<2; ++ii){
            const int i = dh*2 + ii;
            const int cg = n0 + ch*64 + i*16 + rbase;
            float4 b4 = *(const float4*)&B0[cg];
            #pragma unroll
            for (int j=0;j<4;j++){
              const int trl = wtok + j*16 + l15;
              const int tokl = trl >> 2, bb2 = trl & 3;
              #pragma unroll
              for (int r=0;r<4;r++)
                Ts[(ii*16 + rbase + r)*160 + bb2*40 + tokl]
                  = f2bf(acc[i][j][r] + ((const float*)&b4)[r]);
            }
          }
        }
        __syncthreads();
        {
          const int unit = tid >> 1;              // 128 units: 32 d x 4 bb
          const int dl = unit >> 2, bb2 = unit & 3, th = tid & 1;
          unsigned short* dst = Vo + ((size_t)(bb2*16+hh)*64 + dh*32 + dl)*NTOK
                                   + tok0 + th*16;
          const unsigned short* s = &Ts[dl*160 + bb2*40 + th*16];
          *(uint4*)dst       = *(const uint4*)s;
          *(uint4*)(dst + 8) = *(const uint4*)(s + 8);
        }
        __syncthreads();
      }
    }
  } else {
    // rel: fp32 transpose (Tsf[16 c][4 bb][36 tok-pad] = 9.2 KB) -> VALS-T
    float* Tsf = (float*)Ts;
    const int tok0 = m0 >> 2;
    #pragma unroll
    for (int ch=0; ch<2; ++ch){
      #pragma unroll
      for (int i=0;i<4;i++){
        const int e2base = (n0 - 3072) + ch*64 + i*16;   // 16-aligned
        if ((wid >> 1) == ch){
          const int cg = n0 + ch*64 + i*16 + rbase;
          float4 b4 = *(const float4*)&B1[cg - 3072];
          #pragma unroll
          for (int j=0;j<4;j++){
            const int trl = wtok + j*16 + l15;
            const int tokl = trl >> 2, bb2 = trl & 3;
            #pragma unroll
            for (int r=0;r<4;r++)
              Tsf[(rbase + r)*144 + bb2*36 + tokl]
                = acc[i][j][r] + ((const float*)&b4)[r];
          }
        }
        __syncthreads();
        {
          const int pair = tid >> 2, tseg = (tid & 3) * 8; // 64 (c,bb) pairs
          const int c = pair >> 2, bb2 = pair & 3;
          const int nb = e2base >> 4;                      // h = c
          float* dst = VALS + ((size_t)(bb2*32+nb)*16 + c)*NTOK + tok0 + tseg;
          const float* s = &Tsf[c*144 + bb2*36 + tseg];
          *(float4*)dst       = *(const float4*)s;
          *(float4*)(dst + 4) = *(const float4*)(s + 4);
        }
        __syncthreads();
      }
    }
  }
}

// ---------------------------------------------------------------------------
// MFMA flash attention, occupancy-split (R10 verbatim — verified): block =
// (bh, qt) handles the 3 stream-contexts of one q-tile; grid 512 = 2 blocks/
// CU, paired qt/(7-qt) for constant 27 context-tiles per CU.
// ---------------------------------------------------------------------------
__global__ __launch_bounds__(256, 2)
void fattn(const unsigned short* __restrict__ Q,
           const unsigned short* __restrict__ K,
           const unsigned short* __restrict__ VT,
           const float* __restrict__ VALS,
           const int* __restrict__ IBM,
           const int* __restrict__ IBN,
           unsigned short* __restrict__ OUT)
{
  __shared__ float vls[3][64*33];          // 25344 B
  __shared__ unsigned short Pl[4][16*72];  //  9216 B
  __shared__ int fs[513];
  __shared__ float pex[4][16];
  __shared__ float lar[4][16];

  const int blk = blockIdx.x;
  const int half = blk >> 8, idx = blk & 255;
  const int pr = idx & 3, bh = idx >> 2;
  const int qt = half ? (7 - pr) : pr;
  const int tid = threadIdx.x, wid = tid >> 6, lane = tid & 63;
  const int l15 = lane & 15, q4 = lane >> 4;

  fs[tid]       = IBM[(size_t)tid * T_LEN];
  fs[tid + 256] = IBM[(size_t)(tid + 256) * T_LEN];
  if (tid == 0) fs[512] = IBN[(size_t)511 * (2*T_LEN)];

  int tokbase[3];
  #pragma unroll
  for (int c=0;c<3;c++) tokbase[c] = c*T_LEN + qt*64;

  { // stage 3 VALS tiles from VALS-T [bb][nb][h][tok] (coalesced 32B reads)
    const int nb = tid >> 3, t8 = (tid & 7) * 8;
    const float* vr = VALS + ((size_t)((bh >> 4)*32 + nb)*16 + (bh & 15))*NTOK;
    #pragma unroll
    for (int c=0;c<3;c++){
      float4 a = *(const float4*)(vr + tokbase[c] + t8);
      float4 b = *(const float4*)(vr + tokbase[c] + t8 + 4);
      vls[c][(t8+0)*33 + nb] = a.x; vls[c][(t8+1)*33 + nb] = a.y;
      vls[c][(t8+2)*33 + nb] = a.z; vls[c][(t8+3)*33 + nb] = a.w;
      vls[c][(t8+4)*33 + nb] = b.x; vls[c][(t8+5)*33 + nb] = b.y;
      vls[c][(t8+6)*33 + nb] = b.z; vls[c][(t8+7)*33 + nb] = b.w;
    }
  }

  const unsigned short* Kbh = K  + (size_t)bh*NTOK*64;
  const unsigned short* Vbh = VT + (size_t)bh*64*NTOK;
  const int t = qt*64 + wid*16 + l15;

  bf16x8 bq[3][2];
  #pragma unroll
  for (int c=0;c<3;c++){
    const unsigned short* qp = Q + ((size_t)bh*NTOK + tokbase[c] + wid*16 + l15)*64 + q4*8;
    bq[c][0] = *(const bf16x8*)qp;
    bq[c][1] = *(const bf16x8*)(qp + 32);
  }

  f32x4 o[3][4];
  float lr[3];
  #pragma unroll
  for (int c=0;c<3;c++){
    lr[c] = 0.f;
    #pragma unroll
    for (int jd=0;jd<4;jd++)
      #pragma unroll
      for (int r=0;r<4;r++) o[c][jd][r] = 0.f;
  }
  const f32x4 zero = {0.f,0.f,0.f,0.f};
  unsigned short* Pw = &Pl[wid][0];

  __syncthreads();   // vls/fs ready

  for (int tile = 0; tile <= qt; ++tile) {
    const int u0 = tile * 64;
    bf16x8 ka0[4], ka1[4], vb0[4], vb1[4];
    #pragma unroll
    for (int i=0;i<4;i++){
      const unsigned short* kp = Kbh + (size_t)(u0 + 16*i + l15)*64 + q4*8;
      ka0[i] = *(const bf16x8*)kp;  ka1[i] = *(const bf16x8*)(kp + 32);
      const unsigned short* vp = Vbh + (size_t)(16*i + l15)*NTOK + u0 + q4*8;
      vb0[i] = *(const bf16x8*)vp;  vb1[i] = *(const bf16x8*)(vp + 32);
    }
    #pragma unroll
    for (int c=0;c<3;c++){
      const int relofs = (c >= 1) ? 1 : 0;
      f32x4 st[4];
      #pragma unroll
      for (int i=0;i<4;i++){
        st[i] = __builtin_amdgcn_mfma_f32_16x16x32_bf16(ka0[i], bq[c][0], zero, 0, 0, 0);
        st[i] = __builtin_amdgcn_mfma_f32_16x16x32_bf16(ka1[i], bq[c][1], st[i], 0, 0, 0);
      }
      float lp = 0.f;
      #pragma unroll
      for (int i=0;i<4;i++){
        unsigned short pr4[4];
        #pragma unroll
        for (int r=0;r<4;r++){
          const int u = u0 + 16*i + q4*4 + r;
          const bool ok = (u <= t);
          const int nd = ok ? (t - u + relofs) : 0;
          const float rel = vls[c][(wid*16 + l15)*33 + fs[nd]];
          float p = ok ? __expf(st[i][r] + rel) : 0.f;
          const unsigned short pb = f2bf(p);
          pr4[r] = pb;
          lp += bflo(pb);
        }
        uint2 pk;
        pk.x = (unsigned int)pr4[0] | ((unsigned int)pr4[1] << 16);
        pk.y = (unsigned int)pr4[2] | ((unsigned int)pr4[3] << 16);
        *(uint2*)&Pw[l15*72 + 16*i + q4*4] = pk;
      }
      lp += __shfl_xor(lp, 16);
      lp += __shfl_xor(lp, 32);
      lr[c] += lp;
      bf16x8 ap0 = *(const bf16x8*)&Pw[l15*72 + q4*8];
      bf16x8 ap1 = *(const bf16x8*)&Pw[l15*72 + 32 + q4*8];
      #pragma unroll
      for (int jd=0;jd<4;jd++){
        o[c][jd] = __builtin_amdgcn_mfma_f32_16x16x32_bf16(ap0, vb0[jd], o[c][jd], 0, 0, 0);
        o[c][jd] = __builtin_amdgcn_mfma_f32_16x16x32_bf16(ap1, vb1[jd], o[c][jd], 0, 0, 0);
      }
    }
  }

  // ngram tails: contexts c>=1 add exactly one key at token qtok (bucket fs[0])
  #pragma unroll
  for (int c=1;c<3;c++){
    const int qtok = tokbase[c] + wid*16 + l15;
    const unsigned short* qp2 = Q + ((size_t)bh*NTOK + qtok)*64 + q4*16;
    const unsigned short* kp2 = Kbh + (size_t)qtok*64 + q4*16;
    float s = 0.f;
    #pragma unroll
    for (int cc=0;cc<2;cc++){
      bf16x8 qv = *(const bf16x8*)(qp2 + cc*8);
      bf16x8 kv = *(const bf16x8*)(kp2 + cc*8);
      #pragma unroll
      for (int e=0;e<8;e++) s += (float)qv[e] * (float)kv[e];
    }
    s += __shfl_xor(s, 16);
    s += __shfl_xor(s, 32);
    const float p = __expf(s + vls[c][(wid*16 + l15)*33 + fs[0]]);
    lr[c] += p;
    pex[wid][l15] = p;
    #pragma unroll
    for (int r=0;r<4;r++){
      const int qloc = q4*4 + r;
      const float pq = pex[wid][qloc];
      const int qtk = tokbase[c] + wid*16 + qloc;
      #pragma unroll
      for (int jd=0;jd<4;jd++){
        const float vv = bflo(Vbh[(size_t)(16*jd + l15)*NTOK + qtk]);
        o[c][jd][r] += pq * vv;
      }
    }
  }

  const int b = bh >> 4, h = bh & 15;
  #pragma unroll
  for (int c=0;c<3;c++){
    lar[wid][l15] = lr[c];
    #pragma unroll
    for (int r=0;r<4;r++){
      const int qloc = q4*4 + r;
      const float inv = 1.0f / lar[wid][qloc];
      const int qtk = tokbase[c] + wid*16 + qloc;
      unsigned short* orow = OUT + ((size_t)qtk*BS + b)*EMB + h*64 + l15;
      #pragma unroll
      for (int jd=0;jd<4;jd++)
        orow[16*jd] = f2bf(o[c][jd][r] * inv);
    }
  }
}

// ---------------------------------------------------------------------------
extern "C" void kernel_launch(void* const* d_in, const int* in_sizes, int n_in,
                              void* d_out, int out_size, void* d_ws, size_t ws_size,
                              hipStream_t stream) {
  (void)in_sizes; (void)n_in; (void)out_size; (void)ws_size;
  const float* hidden = (const float*)d_in[0];
  const float* wqkv   = (const float*)d_in[1];
  const float* bqkv   = (const float*)d_in[2];
  const float* relw   = (const float*)d_in[3];
  const float* relb   = (const float*)d_in[4];
  const float* outw   = (const float*)d_in[5];
  const float* outb   = (const float*)d_in[6];
  const int* ibm = (const int*)d_in[9];
  const int* ibn = (const int*)d_in[10];

  // workspace (~62 MB):
  //  Hb bf16 6291456 (hidden cast; reused as ATTb after mgemm<0>)
  //  Wc bf16 3670016 ; Ob bf16 1048576
  //  Qb/Kb bf16 [64 bh][1536 tok][64] ; VTb bf16 [64 bh][64 d][1536 tok]
  //  VALS-T fp32 [4 bb][32 nb][16 h][1536 tok]
  unsigned short* Hb  = (unsigned short*)d_ws;
  unsigned short* Wc  = Hb + (size_t)6291456;
  unsigned short* Ob  = Wc + (size_t)3670016;
  unsigned short* Qb  = Ob + (size_t)1048576;
  unsigned short* Kb  = Qb + (size_t)6291456;
  unsigned short* VTb = Kb + (size_t)6291456;
  float* VLS = (float*)(VTb + (size_t)6291456);
  unsigned short* ATTb = Hb;   // alias: hidden-bf16 dead after mgemm<0>

  cast_k<<<5376, 256, 0, stream>>>(hidden, wqkv, relw, outw, Hb, Wc, Ob);
  mgemm<0><<<dim3(28, 48), 256, 0, stream>>>(Hb, Wc, bqkv, relb,
                                             Qb, Kb, VTb, VLS, nullptr);
  fattn<<<512, 256, 0, stream>>>(Qb, Kb, VTb, VLS, ibm, ibn, ATTb);
  mgemm<1><<<dim3(8, 48), 256, 0, stream>>>(ATTb, Ob, outb, nullptr,
                                            nullptr, nullptr, nullptr, nullptr,
                                            (float*)d_out);
}

// Round 13
// 262.627 us; speedup vs baseline: 1.5459x; 1.5459x over previous
//
#include <hip/hip_runtime.h>
#include <stdint.h>

#define T_LEN 512
#define NTOK  1536   // (1+NGRAM)*T
#define EMB   1024
#define BS    4

typedef __bf16 bf16x8 __attribute__((ext_vector_type(8)));
typedef float  f32x4  __attribute__((ext_vector_type(4)));

__device__ __forceinline__ float bflo(unsigned short u){
  union { unsigned int i; float f; } a; a.i = ((unsigned int)u) << 16; return a.f;
}
__device__ __forceinline__ unsigned short f2bf(float f){
  union { float f; unsigned int i; } v; v.f = f;
  unsigned int x = v.i;
  return (unsigned short)((x + 0x7fffu + ((x >> 16) & 1u)) >> 16); // RNE
}

__device__ __forceinline__ void gld_lds16(const unsigned short* gptr, unsigned short* lptr){
  __builtin_amdgcn_global_load_lds(
      (const __attribute__((address_space(1))) unsigned int*)gptr,
      (__attribute__((address_space(3))) unsigned int*)lptr, 16, 0, 0);
}

// ---------------------------------------------------------------------------
// fp32 -> bf16 cast pre-pass (hidden, wqkv++relw, outw). 8 elems/thread.
// ---------------------------------------------------------------------------
__global__ __launch_bounds__(256)
void cast_k(const float* __restrict__ h, const float* __restrict__ wq,
            const float* __restrict__ rw, const float* __restrict__ ow,
            unsigned short* __restrict__ Hb, unsigned short* __restrict__ Wc,
            unsigned short* __restrict__ Ob)
{
  const size_t e = ((size_t)blockIdx.x * 256 + threadIdx.x) * 8;
  const float* src; unsigned short* dst;
  if (e < 6291456)            { src = h  + e;                 dst = Hb + e; }
  else if (e < 9437184)       { size_t o = e - 6291456;       src = wq + o; dst = Wc + o; }
  else if (e < 9961472)       { size_t o = e - 9437184;       src = rw + o; dst = Wc + 3145728 + o; }
  else                        { size_t o = e - 9961472;       src = ow + o; dst = Ob + o; }
  float4 f0 = *(const float4*)src, f1 = *(const float4*)(src + 4);
  unsigned short r[8];
  r[0]=f2bf(f0.x); r[1]=f2bf(f0.y); r[2]=f2bf(f0.z); r[3]=f2bf(f0.w);
  r[4]=f2bf(f1.x); r[5]=f2bf(f1.y); r[6]=f2bf(f1.z); r[7]=f2bf(f1.w);
  *(uint4*)dst = *(const uint4*)r;
}

// ---------------------------------------------------------------------------
// bf16 MFMA GEMM, C^T orientation — R9-exact K-loop (LDS staging + 2-barrier;
// R12 proved LDS-free direct-fragment loads quadruple L1/L2 traffic and tank
// MfmaUtil 21->9%). MODE0 adds an XCD-locality swizzle: 1D grid 1344,
// bid%8 = XCD (round-robin heuristic), each XCD gets a compact 14x12 region
// of the 28x48 (cols x tokens) tile space, x fastest -> per-XCD L2 working
// set ~3.7MB W (reused 12x) + streamed A.
// Epilogue (R9-verbatim): Q/K direct 32B-sector uint2; V via 10KB LDS
// transpose -> VT[bh][d][tok]; rel via fp32 transpose -> VALS-T.
// MODE 1: 64-token tiles, float4 stores.
// ---------------------------------------------------------------------------
template<int MODE>
__global__ __launch_bounds__(256)
void mgemm(const unsigned short* __restrict__ A,
           const unsigned short* __restrict__ W,
           const float* __restrict__ B0,
           const float* __restrict__ B1,
           unsigned short* __restrict__ Qo, unsigned short* __restrict__ Ko,
           unsigned short* __restrict__ Vo, float* __restrict__ VALS,
           float* __restrict__ OUT)
{
  constexpr int TM = (MODE == 0) ? 128 : 64;
  constexpr int NI = (MODE == 0) ? 4 : 2;
  __shared__ __align__(16) unsigned short SM[(TM + 128) * 32];
  unsigned short* As = SM;
  unsigned short* Bs = SM + TM*32;
  const int K = 1024;
  int bx, by;
  if (MODE == 0) {
    const int bid = blockIdx.x;            // 1D grid 1344
    const int xcd = bid & 7, s = bid >> 3; // s in [0,168)
    const int rx = xcd >> 2, ry = xcd & 3; // 2x4 region grid
    bx = rx*14 + (s % 14);                 // 14 col-panels per region
    by = ry*12 + (s / 14);                 // 12 token-panels per region
  } else { bx = blockIdx.x; by = blockIdx.y; }
  const int m0 = by * TM, n0 = bx * 128;
  const int tid = threadIdx.x;
  const int wid = tid >> 6, lane = tid & 63;
  const int l15 = lane & 15, q8 = (lane >> 4) * 8;
  const int srow = lane >> 2, schunk = (lane & 3) * 8;
  const int wcol = (MODE == 0) ? (wid >> 1) * 64 : wid * 32;
  const int wtok = (MODE == 0) ? (wid & 1) * 64 : 0;

  f32x4 acc[NI][4];
  #pragma unroll
  for (int i=0;i<NI;i++)
    #pragma unroll
    for (int j=0;j<4;j++)
      #pragma unroll
      for (int r=0;r<4;r++) acc[i][j][r] = 0.f;

  for (int k0 = 0; k0 < K; k0 += 32) {
    if (MODE == 0) {
      #pragma unroll
      for (int p = 0; p < 2; ++p) {
        const int r0 = p*64 + wid*16;
        gld_lds16(A + (size_t)(m0 + r0 + srow)*K + k0 + schunk, &As[r0*32]);
      }
    } else {
      const int r0 = wid*16;
      gld_lds16(A + (size_t)(m0 + r0 + srow)*K + k0 + schunk, &As[r0*32]);
    }
    #pragma unroll
    for (int p = 0; p < 2; ++p) {
      const int r0 = p*64 + wid*16;
      gld_lds16(W + (size_t)(n0 + r0 + srow)*K + k0 + schunk, &Bs[r0*32]);
    }
    __syncthreads();
    bf16x8 wf[NI], hf[4];
    #pragma unroll
    for (int i=0;i<NI;i++) wf[i] = *(const bf16x8*)&Bs[(wcol + i*16 + l15)*32 + q8];
    #pragma unroll
    for (int j=0;j<4;j++)  hf[j] = *(const bf16x8*)&As[(wtok + j*16 + l15)*32 + q8];
    #pragma unroll
    for (int i=0;i<NI;i++)
      #pragma unroll
      for (int j=0;j<4;j++)
        acc[i][j] = __builtin_amdgcn_mfma_f32_16x16x32_bf16(wf[i], hf[j], acc[i][j], 0, 0, 0);
    __syncthreads();
  }
  // D layout per lane: n(token-local)=l15(+16j+wtok), m(out-col)=rbase+r(+16i+wcol)
  const int rbase = (lane >> 4) * 4;

  if (MODE == 1) {
    #pragma unroll
    for (int i=0;i<NI;i++){
      const int c0l = wcol + i*16 + rbase;
      float4 b4 = *(const float4*)&B0[n0 + c0l];
      #pragma unroll
      for (int j=0;j<4;j++){
        const int tokrow = m0 + j*16 + l15;
        float4 st; st.x=acc[i][j][0]+b4.x; st.y=acc[i][j][1]+b4.y;
        st.z=acc[i][j][2]+b4.z; st.w=acc[i][j][3]+b4.w;
        *(float4*)&OUT[(size_t)tokrow*EMB + n0 + c0l] = st;
      }
    }
    return;
  }

  // ---------------- MODE 0 epilogue ----------------
  if (n0 < 2048) {
    // Q or K: direct uint2 (32B-sector-aligned across q4 lanes)
    const float sc = (n0 < 1024) ? 0.125f : 1.0f;
    unsigned short* base = (n0 < 1024) ? Qo : Ko;
    #pragma unroll
    for (int i=0;i<4;i++){
      const int cg = n0 + wcol + i*16 + rbase;
      const int hh = (cg & 1023) >> 6;
      const int d0 = cg & 63;
      float4 b4 = *(const float4*)&B0[cg];
      #pragma unroll
      for (int j=0;j<4;j++){
        const int tokrow = m0 + wtok + j*16 + l15;
        const int tok = tokrow >> 2, bb2 = tokrow & 3;
        unsigned short pk[4];
        pk[0]=f2bf((acc[i][j][0]+b4.x)*sc); pk[1]=f2bf((acc[i][j][1]+b4.y)*sc);
        pk[2]=f2bf((acc[i][j][2]+b4.z)*sc); pk[3]=f2bf((acc[i][j][3]+b4.w)*sc);
        *(uint2*)&base[((size_t)(bb2*16+hh)*NTOK + tok)*64 + d0] = *(const uint2*)pk;
      }
    }
  } else if (n0 < 3072) {
    // V: transpose via LDS (Ts[32 d][4 bb][40 tok-pad] shorts = 10.2 KB)
    unsigned short* Ts = SM;
    const int tok0 = m0 >> 2;
    #pragma unroll
    for (int ch=0; ch<2; ++ch){
      const int hh = ((n0 + ch*64) & 1023) >> 6;
      #pragma unroll
      for (int dh=0; dh<2; ++dh){
        if ((wid >> 1) == ch){
          #pragma unroll
          for (int ii=0; ii<2; ++ii){
            const int i = dh*2 + ii;
            const int cg = n0 + ch*64 + i*16 + rbase;
            float4 b4 = *(const float4*)&B0[cg];
            #pragma unroll
            for (int j=0;j<4;j++){
              const int trl = wtok + j*16 + l15;
              const int tokl = trl >> 2, bb2 = trl & 3;
              #pragma unroll
              for (int r=0;r<4;r++)
                Ts[(ii*16 + rbase + r)*160 + bb2*40 + tokl]
                  = f2bf(acc[i][j][r] + ((const float*)&b4)[r]);
            }
          }
        }
        __syncthreads();
        {
          const int unit = tid >> 1;              // 128 units: 32 d x 4 bb
          const int dl = unit >> 2, bb2 = unit & 3, th = tid & 1;
          unsigned short* dst = Vo + ((size_t)(bb2*16+hh)*64 + dh*32 + dl)*NTOK
                                   + tok0 + th*16;
          const unsigned short* s = &Ts[dl*160 + bb2*40 + th*16];
          *(uint4*)dst       = *(const uint4*)s;
          *(uint4*)(dst + 8) = *(const uint4*)(s + 8);
        }
        __syncthreads();
      }
    }
  } else {
    // rel: fp32 transpose (Tsf[16 c][4 bb][36 tok-pad] = 9.2 KB) -> VALS-T
    float* Tsf = (float*)SM;
    const int tok0 = m0 >> 2;
    #pragma unroll
    for (int ch=0; ch<2; ++ch){
      #pragma unroll
      for (int i=0;i<4;i++){
        const int e2base = (n0 - 3072) + ch*64 + i*16;   // 16-aligned
        if ((wid >> 1) == ch){
          const int cg = n0 + ch*64 + i*16 + rbase;
          float4 b4 = *(const float4*)&B1[cg - 3072];
          #pragma unroll
          for (int j=0;j<4;j++){
            const int trl = wtok + j*16 + l15;
            const int tokl = trl >> 2, bb2 = trl & 3;
            #pragma unroll
            for (int r=0;r<4;r++)
              Tsf[(rbase + r)*144 + bb2*36 + tokl]
                = acc[i][j][r] + ((const float*)&b4)[r];
          }
        }
        __syncthreads();
        {
          const int pair = tid >> 2, tseg = (tid & 3) * 8; // 64 (c,bb) pairs
          const int c = pair >> 2, bb2 = pair & 3;
          const int nb = e2base >> 4;                      // h = c
          float* dst = VALS + ((size_t)(bb2*32+nb)*16 + c)*NTOK + tok0 + tseg;
          const float* s = &Tsf[c*144 + bb2*36 + tseg];
          *(float4*)dst       = *(const float4*)s;
          *(float4*)(dst + 4) = *(const float4*)(s + 4);
        }
        __syncthreads();
      }
    }
  }
}

// ---------------------------------------------------------------------------
// MFMA flash attention, occupancy-split (R10 verbatim — verified): block =
// (bh, qt) handles the 3 stream-contexts of one q-tile; grid 512 = 2 blocks/
// CU, paired qt/(7-qt) for constant 27 context-tiles per CU.
// ---------------------------------------------------------------------------
__global__ __launch_bounds__(256, 2)
void fattn(const unsigned short* __restrict__ Q,
           const unsigned short* __restrict__ K,
           const unsigned short* __restrict__ VT,
           const float* __restrict__ VALS,
           const int* __restrict__ IBM,
           const int* __restrict__ IBN,
           unsigned short* __restrict__ OUT)
{
  __shared__ float vls[3][64*33];          // 25344 B
  __shared__ unsigned short Pl[4][16*72];  //  9216 B
  __shared__ int fs[513];
  __shared__ float pex[4][16];
  __shared__ float lar[4][16];

  const int blk = blockIdx.x;
  const int half = blk >> 8, idx = blk & 255;
  const int pr = idx & 3, bh = idx >> 2;
  const int qt = half ? (7 - pr) : pr;
  const int tid = threadIdx.x, wid = tid >> 6, lane = tid & 63;
  const int l15 = lane & 15, q4 = lane >> 4;

  fs[tid]       = IBM[(size_t)tid * T_LEN];
  fs[tid + 256] = IBM[(size_t)(tid + 256) * T_LEN];
  if (tid == 0) fs[512] = IBN[(size_t)511 * (2*T_LEN)];

  int tokbase[3];
  #pragma unroll
  for (int c=0;c<3;c++) tokbase[c] = c*T_LEN + qt*64;

  { // stage 3 VALS tiles from VALS-T [bb][nb][h][tok] (coalesced 32B reads)
    const int nb = tid >> 3, t8 = (tid & 7) * 8;
    const float* vr = VALS + ((size_t)((bh >> 4)*32 + nb)*16 + (bh & 15))*NTOK;
    #pragma unroll
    for (int c=0;c<3;c++){
      float4 a = *(const float4*)(vr + tokbase[c] + t8);
      float4 b = *(const float4*)(vr + tokbase[c] + t8 + 4);
      vls[c][(t8+0)*33 + nb] = a.x; vls[c][(t8+1)*33 + nb] = a.y;
      vls[c][(t8+2)*33 + nb] = a.z; vls[c][(t8+3)*33 + nb] = a.w;
      vls[c][(t8+4)*33 + nb] = b.x; vls[c][(t8+5)*33 + nb] = b.y;
      vls[c][(t8+6)*33 + nb] = b.z; vls[c][(t8+7)*33 + nb] = b.w;
    }
  }

  const unsigned short* Kbh = K  + (size_t)bh*NTOK*64;
  const unsigned short* Vbh = VT + (size_t)bh*64*NTOK;
  const int t = qt*64 + wid*16 + l15;

  bf16x8 bq[3][2];
  #pragma unroll
  for (int c=0;c<3;c++){
    const unsigned short* qp = Q + ((size_t)bh*NTOK + tokbase[c] + wid*16 + l15)*64 + q4*8;
    bq[c][0] = *(const bf16x8*)qp;
    bq[c][1] = *(const bf16x8*)(qp + 32);
  }

  f32x4 o[3][4];
  float lr[3];
  #pragma unroll
  for (int c=0;c<3;c++){
    lr[c] = 0.f;
    #pragma unroll
    for (int jd=0;jd<4;jd++)
      #pragma unroll
      for (int r=0;r<4;r++) o[c][jd][r] = 0.f;
  }
  const f32x4 zero = {0.f,0.f,0.f,0.f};
  unsigned short* Pw = &Pl[wid][0];

  __syncthreads();   // vls/fs ready

  for (int tile = 0; tile <= qt; ++tile) {
    const int u0 = tile * 64;
    bf16x8 ka0[4], ka1[4], vb0[4], vb1[4];
    #pragma unroll
    for (int i=0;i<4;i++){
      const unsigned short* kp = Kbh + (size_t)(u0 + 16*i + l15)*64 + q4*8;
      ka0[i] = *(const bf16x8*)kp;  ka1[i] = *(const bf16x8*)(kp + 32);
      const unsigned short* vp = Vbh + (size_t)(16*i + l15)*NTOK + u0 + q4*8;
      vb0[i] = *(const bf16x8*)vp;  vb1[i] = *(const bf16x8*)(vp + 32);
    }
    #pragma unroll
    for (int c=0;c<3;c++){
      const int relofs = (c >= 1) ? 1 : 0;
      f32x4 st[4];
      #pragma unroll
      for (int i=0;i<4;i++){
        st[i] = __builtin_amdgcn_mfma_f32_16x16x32_bf16(ka0[i], bq[c][0], zero, 0, 0, 0);
        st[i] = __builtin_amdgcn_mfma_f32_16x16x32_bf16(ka1[i], bq[c][1], st[i], 0, 0, 0);
      }
      float lp = 0.f;
      #pragma unroll
      for (int i=0;i<4;i++){
        unsigned short pr4[4];
        #pragma unroll
        for (int r=0;r<4;r++){
          const int u = u0 + 16*i + q4*4 + r;
          const bool ok = (u <= t);
          const int nd = ok ? (t - u + relofs) : 0;
          const float rel = vls[c][(wid*16 + l15)*33 + fs[nd]];
          float p = ok ? __expf(st[i][r] + rel) : 0.f;
          const unsigned short pb = f2bf(p);
          pr4[r] = pb;
          lp += bflo(pb);
        }
        uint2 pk;
        pk.x = (unsigned int)pr4[0] | ((unsigned int)pr4[1] << 16);
        pk.y = (unsigned int)pr4[2] | ((unsigned int)pr4[3] << 16);
        *(uint2*)&Pw[l15*72 + 16*i + q4*4] = pk;
      }
      lp += __shfl_xor(lp, 16);
      lp += __shfl_xor(lp, 32);
      lr[c] += lp;
      bf16x8 ap0 = *(const bf16x8*)&Pw[l15*72 + q4*8];
      bf16x8 ap1 = *(const bf16x8*)&Pw[l15*72 + 32 + q4*8];
      #pragma unroll
      for (int jd=0;jd<4;jd++){
        o[c][jd] = __builtin_amdgcn_mfma_f32_16x16x32_bf16(ap0, vb0[jd], o[c][jd], 0, 0, 0);
        o[c][jd] = __builtin_amdgcn_mfma_f32_16x16x32_bf16(ap1, vb1[jd], o[c][jd], 0, 0, 0);
      }
    }
  }

  // ngram tails: contexts c>=1 add exactly one key at token qtok (bucket fs[0])
  #pragma unroll
  for (int c=1;c<3;c++){
    const int qtok = tokbase[c] + wid*16 + l15;
    const unsigned short* qp2 = Q + ((size_t)bh*NTOK + qtok)*64 + q4*16;
    const unsigned short* kp2 = Kbh + (size_t)qtok*64 + q4*16;
    float s = 0.f;
    #pragma unroll
    for (int cc=0;cc<2;cc++){
      bf16x8 qv = *(const bf16x8*)(qp2 + cc*8);
      bf16x8 kv = *(const bf16x8*)(kp2 + cc*8);
      #pragma unroll
      for (int e=0;e<8;e++) s += (float)qv[e] * (float)kv[e];
    }
    s += __shfl_xor(s, 16);
    s += __shfl_xor(s, 32);
    const float p = __expf(s + vls[c][(wid*16 + l15)*33 + fs[0]]);
    lr[c] += p;
    pex[wid][l15] = p;
    #pragma unroll
    for (int r=0;r<4;r++){
      const int qloc = q4*4 + r;
      const float pq = pex[wid][qloc];
      const int qtk = tokbase[c] + wid*16 + qloc;
      #pragma unroll
      for (int jd=0;jd<4;jd++){
        const float vv = bflo(Vbh[(size_t)(16*jd + l15)*NTOK + qtk]);
        o[c][jd][r] += pq * vv;
      }
    }
  }

  const int b = bh >> 4, h = bh & 15;
  #pragma unroll
  for (int c=0;c<3;c++){
    lar[wid][l15] = lr[c];
    #pragma unroll
    for (int r=0;r<4;r++){
      const int qloc = q4*4 + r;
      const float inv = 1.0f / lar[wid][qloc];
      const int qtk = tokbase[c] + wid*16 + qloc;
      unsigned short* orow = OUT + ((size_t)qtk*BS + b)*EMB + h*64 + l15;
      #pragma unroll
      for (int jd=0;jd<4;jd++)
        orow[16*jd] = f2bf(o[c][jd][r] * inv);
    }
  }
}

// ---------------------------------------------------------------------------
extern "C" void kernel_launch(void* const* d_in, const int* in_sizes, int n_in,
                              void* d_out, int out_size, void* d_ws, size_t ws_size,
                              hipStream_t stream) {
  (void)in_sizes; (void)n_in; (void)out_size; (void)ws_size;
  const float* hidden = (const float*)d_in[0];
  const float* wqkv   = (const float*)d_in[1];
  const float* bqkv   = (const float*)d_in[2];
  const float* relw   = (const float*)d_in[3];
  const float* relb   = (const float*)d_in[4];
  const float* outw   = (const float*)d_in[5];
  const float* outb   = (const float*)d_in[6];
  const int* ibm = (const int*)d_in[9];
  const int* ibn = (const int*)d_in[10];

  // workspace (~62 MB):
  //  Hb bf16 6291456 (hidden cast; reused as ATTb after mgemm<0>)
  //  Wc bf16 3670016 ; Ob bf16 1048576
  //  Qb/Kb bf16 [64 bh][1536 tok][64] ; VTb bf16 [64 bh][64 d][1536 tok]
  //  VALS-T fp32 [4 bb][32 nb][16 h][1536 tok]
  unsigned short* Hb  = (unsigned short*)d_ws;
  unsigned short* Wc  = Hb + (size_t)6291456;
  unsigned short* Ob  = Wc + (size_t)3670016;
  unsigned short* Qb  = Ob + (size_t)1048576;
  unsigned short* Kb  = Qb + (size_t)6291456;
  unsigned short* VTb = Kb + (size_t)6291456;
  float* VLS = (float*)(VTb + (size_t)6291456);
  unsigned short* ATTb = Hb;   // alias: hidden-bf16 dead after mgemm<0>

  cast_k<<<5376, 256, 0, stream>>>(hidden, wqkv, relw, outw, Hb, Wc, Ob);
  mgemm<0><<<1344, 256, 0, stream>>>(Hb, Wc, bqkv, relb,
                                     Qb, Kb, VTb, VLS, nullptr);
  fattn<<<512, 256, 0, stream>>>(Qb, Kb, VTb, VLS, ibm, ibn, ATTb);
  mgemm<1><<<dim3(8, 96), 256, 0, stream>>>(ATTb, Ob, outb, nullptr,
                                            nullptr, nullptr, nullptr, nullptr,
                                            (float*)d_out);
}